// Round 3
// baseline (242.818 us; speedup 1.0000x reference)
//
#include <hip/hip_runtime.h>
#include <stdint.h>

// S6Layer on MI355X. B=8, L=4096, DM=256, DI=384, DS=8, CHUNK=32.
// R5 GEMM: weights-stationary B panel in LDS (one barrier) + per-wave-private
// A staging via global_load_lds double-buffer with EXPLICIT s_waitcnt vmcnt(N).
// R6: vmcnt waits as inline-asm + sched_barrier(0) AFTER the wait (RAW fence).
// R8 FIX (this round): R2 bench proved a remaining WAR race — post-timing
// output diverged (0.0957 -> 0.125 across graph replays). After full unroll
// the scheduler could hoist the global_load_lds DMA (chunk k+2 -> buf[k])
// ABOVE the ds_reads of buf[k] in the same sched region; with A rows L2-hot
// (reused by up to 18 N-panels) the DMA return can beat a queued ds_read.
// Fix: sched_barrier(0) BEFORE the DMA issues too -> strictly alternating
// [reads+MFMA] | [DMA issue + counted vmcnt] regions; both hazard directions
// fenced, chunk k+1 still in flight during compute of k (overlap preserved).
// Deterministic bf16 floor estimate ~0.01 vs threshold 0.1075.
// Epilogue LDS staging pad 72 (R4: 983k bank conflicts at stride 64).
#define B_  8
#define L_  4096
#define DM  256
#define DI  384
#define DS  8
#define M_  (B_*L_)   // 32768 tokens

typedef float f32x4 __attribute__((ext_vector_type(4)));
typedef short s16x8 __attribute__((ext_vector_type(8)));

#define AS1(p) ((__attribute__((address_space(1))) void*)(p))
#define AS3(p) ((__attribute__((address_space(3))) void*)(p))

__device__ __forceinline__ unsigned short f2bf(float f) {
  union { float f; uint32_t u; } v; v.f = f;
  uint32_t r = v.u + 0x7FFFu + ((v.u >> 16) & 1u);   // RNE
  return (unsigned short)(r >> 16);
}
__device__ __forceinline__ float bf2f(unsigned short h) {
  union { uint32_t u; float f; } v; v.u = ((uint32_t)h) << 16;
  return v.f;
}
__device__ __forceinline__ float silu_f(float x) { return x / (1.f + __expf(-x)); }

// ---------------- weight fp32 -> bf16 ----------------
__global__ __launch_bounds__(256) void cvt_kernel(
    const float* __restrict__ w0, const float* __restrict__ w1, const float* __restrict__ w2,
    unsigned short* __restrict__ o0, unsigned short* __restrict__ o1, unsigned short* __restrict__ o2) {
  int i = blockIdx.x * 256 + threadIdx.x;
  if (i < 3*DI*DM) o0[i] = f2bf(w0[i]);
  if (i < DI*DI)   o1[i] = f2bf(w1[i]);
  if (i < DM*DI)   o2[i] = f2bf(w2[i]);
}

// ---------------- layernorm: one wave per token ----------------
__global__ __launch_bounds__(256) void ln_kernel(
    const float* __restrict__ x, const float* __restrict__ gamma, const float* __restrict__ beta,
    unsigned short* __restrict__ xn) {
  int token = blockIdx.x * 4 + (threadIdx.x >> 6);
  int lane  = threadIdx.x & 63;
  const float4 v = *(const float4*)(x + (size_t)token*DM + lane*4);
  float s  = v.x + v.y + v.z + v.w;
  float ss = v.x*v.x + v.y*v.y + v.z*v.z + v.w*v.w;
  #pragma unroll
  for (int off = 32; off > 0; off >>= 1) {
    s  += __shfl_xor(s,  off, 64);
    ss += __shfl_xor(ss, off, 64);
  }
  float mean = s * (1.f/DM);
  float var  = ss * (1.f/DM) - mean*mean;
  float rstd = rsqrtf(var + 1e-5f);
  const float4 g = *(const float4*)(gamma + lane*4);
  const float4 b = *(const float4*)(beta  + lane*4);
  ushort4 o;
  o.x = f2bf((v.x - mean)*rstd*g.x + b.x);
  o.y = f2bf((v.y - mean)*rstd*g.y + b.y);
  o.z = f2bf((v.z - mean)*rstd*g.z + b.z);
  o.w = f2bf((v.w - mean)*rstd*g.w + b.w);
  *(ushort4*)(xn + (size_t)token*DM + lane*4) = o;
}

// ---------------- weights-stationary MFMA GEMM, per-wave async A pipeline ----
// C[M,N] = A[M,K] @ Bw[N,K]^T. Block: 256 thr (4 waves), tile 128M x 64N;
// wave w owns rows w*32..w*32+31 (2 mi tiles) x all 64 N (4 ni tiles).
// LDS: B panel 64xK (swizzled 16B chunks, uniform 8-lanes/bank-quad on b128
// reads) + per-wave A double-buffer (2 x 2KB; chunk = 32 rows x 32 k).
// K-loop regions (sched_barrier-fenced, alternating):
//   [DMA issue chunk kt+1 -> buf[(kt+1)&1] ; s_waitcnt vmcnt(2)]
//   [ds_read buf[kt&1] frags ; 8 MFMAs]
// No K-loop s_barrier; the counted vmcnt keeps chunk kt+1 in flight during
// compute of kt (AITER-style never-drain).
template<int EPI, int KSTEPS>
__global__ __launch_bounds__(256, 2) void gemm_ws(
    const unsigned short* __restrict__ A,   // [M,K] bf16
    const unsigned short* __restrict__ Bw,  // [N,K] bf16
    const float* __restrict__ bias,         // [N]
    unsigned short* __restrict__ o_xp, unsigned short* __restrict__ o_z,
    unsigned short* __restrict__ o_dtin,    // EPI=1
    unsigned short* __restrict__ o_bf,      // EPI=2
    const float* __restrict__ resid, float* __restrict__ o_f)  // EPI=3
{
  constexpr int K    = KSTEPS * 32;
  constexpr int CPR  = K / 8;               // 16B chunks per B row
  constexpr int SM_E = 64*K + 8192;         // B panel + 4 waves x 2 bufs x 1024 elems
  __shared__ unsigned short smem[SM_E];     // 64KB (K=384) / 48KB (K=256)
  unsigned short* sB = smem;

  const int t    = threadIdx.x;
  const int lane = t & 63;
  const int w    = t >> 6;
  const int fr   = lane & 15;
  const int fq   = lane >> 4;
  const int mbase = blockIdx.x * 128;
  const int nbase = blockIdx.y * 64;
  const int wm   = w * 32;
  unsigned short* sAw = smem + 64*K + w*2048;   // wave-private: 2 bufs x 1024 elems

  // ---- stage B panel (once): LDS slot c holds swizzled global chunk ----
  #pragma unroll
  for (int i = 0; i < (64*CPR)/256; ++i) {
    int c   = i*256 + t;
    int row = c / CPR;
    int j   = c - row*CPR;
    int jp  = (j & ~7) | ((j & 7) ^ (row & 7));
    __builtin_amdgcn_global_load_lds(AS1(Bw + (size_t)(nbase + row)*K + jp*8),
                                     AS3(sB + c*8), 16, 0, 0);
  }

  // ---- A global pointers: instr i covers rows i*16+(lane>>2), 16B chunk lane&3
  const unsigned short* gA[2];
  #pragma unroll
  for (int i = 0; i < 2; ++i)
    gA[i] = A + (size_t)(mbase + wm + i*16 + (lane >> 2)) * K + (lane & 3)*8;

  // preload chunk 0 into buf 0 (HW scatters lane -> +lane*16B)
  #pragma unroll
  for (int i = 0; i < 2; ++i)
    __builtin_amdgcn_global_load_lds(AS1(gA[i]), AS3(sAw + i*512), 16, 0, 0);

  f32x4 acc[2][4];
  #pragma unroll
  for (int mi = 0; mi < 2; ++mi)
    #pragma unroll
    for (int ni = 0; ni < 4; ++ni) acc[mi][ni] = (f32x4){0.f, 0.f, 0.f, 0.f};

  __syncthreads();   // B (and chunk0) resident; only barrier before epilogue

  #pragma unroll
  for (int kt = 0; kt < KSTEPS; ++kt) {
    // Seal previous compute region: all ds_reads of buf[(kt+1)&1] (read at
    // kt-1) are issued AND lgkm-waited before any DMA may overwrite it (WAR).
    __builtin_amdgcn_sched_barrier(0);
    if (kt + 1 < KSTEPS) {
      unsigned short* dstb = sAw + ((kt+1) & 1)*1024;
      #pragma unroll
      for (int i = 0; i < 2; ++i)
        __builtin_amdgcn_global_load_lds(AS1(gA[i] + (kt+1)*32), AS3(dstb + i*512), 16, 0, 0);
      // chunk kt retired, chunk kt+1 (2 loads) still in flight
      asm volatile("s_waitcnt vmcnt(2)" ::: "memory");
    } else {
      asm volatile("s_waitcnt vmcnt(0)" ::: "memory");   // last chunk resident
    }
    // Seal DMA region: no ds_read below may hoist above the wait (RAW).
    __builtin_amdgcn_sched_barrier(0);
    const unsigned short* rbuf = sAw + (kt & 1)*1024;
    s16x8 af[2], bfr[4];
    #pragma unroll
    for (int mi = 0; mi < 2; ++mi)
      af[mi] = *(const s16x8*)(rbuf + mi*512 + fr*32 + fq*8);
    #pragma unroll
    for (int ni = 0; ni < 4; ++ni) {
      int r    = ni*16 + fr;
      int j    = kt*4 + fq;
      int slot = (j & ~7) | ((j & 7) ^ (r & 7));
      bfr[ni]  = *(const s16x8*)(sB + r*K + slot*8);
    }
    #pragma unroll
    for (int mi = 0; mi < 2; ++mi)
      #pragma unroll
      for (int ni = 0; ni < 4; ++ni)
        acc[mi][ni] = __builtin_amdgcn_mfma_f32_16x16x32_bf16(af[mi], bfr[ni], acc[mi][ni], 0, 0, 0);
  }

  // ---- epilogue: C layout per 16x16 tile: col=fr, row=fq*4+r (m89) ----
  if constexpr (EPI == 3) {
    #pragma unroll
    for (int ni = 0; ni < 4; ++ni) {
      int gn = nbase + ni*16 + fr;
      float bv = bias[gn];
      #pragma unroll
      for (int mi = 0; mi < 2; ++mi) {
        int gm0 = mbase + wm + mi*16 + fq*4;
        #pragma unroll
        for (int r = 0; r < 4; ++r) {
          size_t gm = (size_t)(gm0 + r);
          o_f[gm*DM + gn] = acc[mi][ni][r] + bv + resid[gm*DM + gn];
        }
      }
    }
  } else {
    __syncthreads();   // all waves done with sB/sA -> reuse for C staging
    const bool do_silu = (EPI == 1) && (blockIdx.y < 12);   // panels 0-5 xp, 6-11 z
    // stage with pad-72 row stride (144B == 4 mod 32 banks -> ~2-way on writes)
    #pragma unroll
    for (int ni = 0; ni < 4; ++ni) {
      int cn = ni*16 + fr;
      float bv = bias[nbase + cn];
      #pragma unroll
      for (int mi = 0; mi < 2; ++mi) {
        int rm0 = wm + mi*16 + fq*4;
        #pragma unroll
        for (int r = 0; r < 4; ++r) {
          float c = acc[mi][ni][r] + bv;
          if constexpr (EPI == 1) { if (do_silu) c = silu_f(c); }
          else                    { c = (c > 20.f) ? c : log1pf(__expf(c)); }
          smem[(rm0 + r)*72 + cn] = f2bf(c);
        }
      }
    }
    __syncthreads();
    unsigned short* dst;
    int colbase;
    if constexpr (EPI == 1) {
      int p = blockIdx.y;                       // 0..17
      dst = (p < 6) ? o_xp : (p < 12) ? o_z : o_dtin;
      colbase = (p % 6) * 64;
    } else {
      dst = o_bf; colbase = nbase;
    }
    const int rr = t >> 3, cc = (t & 7) * 8;
    #pragma unroll
    for (int it = 0; it < 4; ++it) {
      int row = rr + it*32;
      s16x8 v = *(const s16x8*)(smem + row*72 + cc);
      *(s16x8*)(dst + (size_t)(mbase + row)*DI + colbase + cc) = v;
    }
  }
}

// ---------------- chunked selective scan ----------------
__global__ __launch_bounds__(384) void scan_kernel(
    const unsigned short* __restrict__ xp, const unsigned short* __restrict__ dt,
    const unsigned short* __restrict__ zb, const float* __restrict__ A_log,
    const float* __restrict__ D_vec, unsigned short* __restrict__ yz) {
  int g  = blockIdx.x;
  int di = threadIdx.x;
  size_t base = (size_t)g * 32 * DI + di;
  float a[DS];
  #pragma unroll
  for (int s = 0; s < DS; ++s) a[s] = -__expf(A_log[di*DS + s]);
  float Dv = D_vec[di];
  float h[DS] = {0.f,0.f,0.f,0.f,0.f,0.f,0.f,0.f};
  for (int tt = 0; tt < 32; ++tt) {
    size_t idx = base + (size_t)tt * DI;
    float xv  = bf2f(xp[idx]);
    float dtv = bf2f(dt[idx]);
    float y = 0.f;
    #pragma unroll
    for (int s = 0; s < DS; ++s) {
      h[s] = h[s] * __expf(dtv * a[s]) + xv;
      y += h[s];
    }
    float zv = bf2f(zb[idx]);
    yz[idx] = f2bf(y * zv + xv * Dv);
  }
}

extern "C" void kernel_launch(void* const* d_in, const int* in_sizes, int n_in,
                              void* d_out, int out_size, void* d_ws, size_t ws_size,
                              hipStream_t stream) {
  const float* x     = (const float*)d_in[0];
  const float* gamma = (const float*)d_in[1];
  const float* beta  = (const float*)d_in[2];
  const float* W_in  = (const float*)d_in[3];
  const float* b_in  = (const float*)d_in[4];
  const float* W_dt  = (const float*)d_in[5];
  const float* b_dt  = (const float*)d_in[6];
  const float* A_log = (const float*)d_in[7];
  const float* D_vec = (const float*)d_in[8];
  const float* W_out = (const float*)d_in[9];
  const float* b_out = (const float*)d_in[10];
  float* out = (float*)d_out;

  char* ws = (char*)d_ws;
  size_t off = 0;
  auto alloc = [&](size_t bytes) -> char* {
    char* p = ws + off; off += (bytes + 255) & ~(size_t)255; return p;
  };
  unsigned short* xn    = (unsigned short*)alloc((size_t)M_*DM*2);
  unsigned short* xpb   = (unsigned short*)alloc((size_t)M_*DI*2);
  unsigned short* zb    = (unsigned short*)alloc((size_t)M_*DI*2);
  unsigned short* dtin  = (unsigned short*)alloc((size_t)M_*DI*2);
  unsigned short* dtb   = (unsigned short*)alloc((size_t)M_*DI*2);
  unsigned short* yzb   = dtin;   // dtin dead after GEMM2 -> reuse for yz
  unsigned short* winb  = (unsigned short*)alloc((size_t)3*DI*DM*2);
  unsigned short* wdtb  = (unsigned short*)alloc((size_t)DI*DI*2);
  unsigned short* woutb = (unsigned short*)alloc((size_t)DM*DI*2);

  cvt_kernel<<<dim3((3*DI*DM + 255)/256), 256, 0, stream>>>(W_in, W_dt, W_out, winb, wdtb, woutb);
  ln_kernel<<<dim3(M_/4), 256, 0, stream>>>(x, gamma, beta, xn);
  // GEMM1: xn[M,256] @ W_in[1152,256]^T -> silu(xp), silu(z), dtin
  gemm_ws<1, 8><<<dim3(M_/128, (3*DI)/64), 256, 0, stream>>>(
      xn, winb, b_in, xpb, zb, dtin, nullptr, nullptr, nullptr);
  // GEMM2: dtin[M,384] @ W_dt[384,384]^T ; softplus -> dt
  gemm_ws<2, 12><<<dim3(M_/128, DI/64), 256, 0, stream>>>(
      dtin, wdtb, b_dt, nullptr, nullptr, nullptr, dtb, nullptr, nullptr);
  // scan -> yz = y*z + xp*D
  scan_kernel<<<dim3(M_/32), DI, 0, stream>>>(xpb, dtb, zb, A_log, D_vec, yzb);
  // GEMM3: yz[M,384] @ W_out[256,384]^T + b_out + residual -> out (fp32)
  gemm_ws<3, 12><<<dim3(M_/128, DM/64), 256, 0, stream>>>(
      yzb, woutb, b_out, nullptr, nullptr, nullptr, nullptr, x, out);
}

// Round 4
// 226.573 us; speedup vs baseline: 1.0717x; 1.0717x over previous
//
#include <hip/hip_runtime.h>
#include <stdint.h>

// S6Layer on MI355X. B=8, L=4096, DM=256, DI=384, DS=8, CHUNK=32.
// R9 (this round): K-loop rewrite driven by R3 counters (GEMM2: 62us,
// MfmaUtil 5.9%, VALUBusy 68%, hbm 9%, 1.87M LDS bank conflicts, occ 18.8%).
//  1. A fragments now load DIRECTLY global->VGPR (global_load_dwordx4 with
//     immediate offsets): the MFMA A-frag is 16 contiguous bytes per lane.
//     Kills the LDS round-trip, the vmcnt/sched_barrier serialization, the
//     8-way bank conflict on A ds_reads, and every race path (plain VGPR
//     dependency tracking).
//  2. B swizzled LDS addresses algebraically folded into TWO per-lane base
//     pointers (kt-parity XOR64) + compile-time immediates -> zero per-kt VALU.
//  3. softplus epilogue: log1pf -> __logf(1+__expf) (err << bf16 quantum).
//  LDS 64->48KB (K=384) / 32KB (K=256): occupancy 2->3 / 5 blocks per CU.
// Epilogue LDS staging pad 72 (R4: 983k bank conflicts at stride 64).
#define B_  8
#define L_  4096
#define DM  256
#define DI  384
#define DS  8
#define M_  (B_*L_)   // 32768 tokens

typedef float f32x4 __attribute__((ext_vector_type(4)));
typedef short s16x8 __attribute__((ext_vector_type(8)));

#define AS1(p) ((__attribute__((address_space(1))) void*)(p))
#define AS3(p) ((__attribute__((address_space(3))) void*)(p))

__device__ __forceinline__ unsigned short f2bf(float f) {
  union { float f; uint32_t u; } v; v.f = f;
  uint32_t r = v.u + 0x7FFFu + ((v.u >> 16) & 1u);   // RNE
  return (unsigned short)(r >> 16);
}
__device__ __forceinline__ float bf2f(unsigned short h) {
  union { uint32_t u; float f; } v; v.u = ((uint32_t)h) << 16;
  return v.f;
}
__device__ __forceinline__ float silu_f(float x) { return x / (1.f + __expf(-x)); }

// ---------------- weight fp32 -> bf16 ----------------
__global__ __launch_bounds__(256) void cvt_kernel(
    const float* __restrict__ w0, const float* __restrict__ w1, const float* __restrict__ w2,
    unsigned short* __restrict__ o0, unsigned short* __restrict__ o1, unsigned short* __restrict__ o2) {
  int i = blockIdx.x * 256 + threadIdx.x;
  if (i < 3*DI*DM) o0[i] = f2bf(w0[i]);
  if (i < DI*DI)   o1[i] = f2bf(w1[i]);
  if (i < DM*DI)   o2[i] = f2bf(w2[i]);
}

// ---------------- layernorm: one wave per token ----------------
__global__ __launch_bounds__(256) void ln_kernel(
    const float* __restrict__ x, const float* __restrict__ gamma, const float* __restrict__ beta,
    unsigned short* __restrict__ xn) {
  int token = blockIdx.x * 4 + (threadIdx.x >> 6);
  int lane  = threadIdx.x & 63;
  const float4 v = *(const float4*)(x + (size_t)token*DM + lane*4);
  float s  = v.x + v.y + v.z + v.w;
  float ss = v.x*v.x + v.y*v.y + v.z*v.z + v.w*v.w;
  #pragma unroll
  for (int off = 32; off > 0; off >>= 1) {
    s  += __shfl_xor(s,  off, 64);
    ss += __shfl_xor(ss, off, 64);
  }
  float mean = s * (1.f/DM);
  float var  = ss * (1.f/DM) - mean*mean;
  float rstd = rsqrtf(var + 1e-5f);
  const float4 g = *(const float4*)(gamma + lane*4);
  const float4 b = *(const float4*)(beta  + lane*4);
  ushort4 o;
  o.x = f2bf((v.x - mean)*rstd*g.x + b.x);
  o.y = f2bf((v.y - mean)*rstd*g.y + b.y);
  o.z = f2bf((v.z - mean)*rstd*g.z + b.z);
  o.w = f2bf((v.w - mean)*rstd*g.w + b.w);
  *(ushort4*)(xn + (size_t)token*DM + lane*4) = o;
}

// ---------------- weights-stationary MFMA GEMM, A direct-to-VGPR ----------
// C[M,N] = A[M,K] @ Bw[N,K]^T. Block: 256 thr (4 waves), tile 128M x 64N;
// wave w owns rows w*32..w*32+31 (2 mi tiles) x all 64 N (4 ni tiles).
// LDS: B panel only, 64 x K bf16, staged once via global_load_lds with the
// 16B-chunk XOR swizzle: LDS[row][j] = G[row][(j&~7)|((j&7)^(row&7))].
// K-loop per kt: 2 global_load_dwordx4 (A frags, imm offsets) + 4
// ds_read_b128 (B frags, imm offsets off 2 per-lane bases) + 8 MFMA.
// No barriers, no manual waitcnt: compiler pipelines A loads across kt.
template<int EPI, int KSTEPS>
__global__ __launch_bounds__(256, 3) void gemm_ws(
    const unsigned short* __restrict__ A,   // [M,K] bf16
    const unsigned short* __restrict__ Bw,  // [N,K] bf16
    const float* __restrict__ bias,         // [N]
    unsigned short* __restrict__ o_xp, unsigned short* __restrict__ o_z,
    unsigned short* __restrict__ o_dtin,    // EPI=1
    unsigned short* __restrict__ o_bf,      // EPI=2
    const float* __restrict__ resid, float* __restrict__ o_f)  // EPI=3
{
  constexpr int K    = KSTEPS * 32;
  constexpr int CPR  = K / 8;               // 16B chunks per B row
  __shared__ unsigned short smem[64*K];     // 48KB (K=384) / 32KB (K=256)
  unsigned short* sB = smem;

  const int t    = threadIdx.x;
  const int lane = t & 63;
  const int w    = t >> 6;
  const int fr   = lane & 15;
  const int fq   = lane >> 4;
  const int mbase = blockIdx.x * 128;
  const int nbase = blockIdx.y * 64;
  const int wm   = w * 32;

  // ---- stage B panel (once): LDS slot c holds swizzled global chunk ----
  #pragma unroll
  for (int i = 0; i < (64*CPR)/256; ++i) {
    int c   = i*256 + t;
    int row = c / CPR;
    int j   = c - row*CPR;
    int jp  = (j & ~7) | ((j & 7) ^ (row & 7));
    __builtin_amdgcn_global_load_lds(AS1(Bw + (size_t)(nbase + row)*K + jp*8),
                                     AS3(sB + c*8), 16, 0, 0);
  }

  // ---- A fragment base: af[mi][kt] = A[mbase+wm+mi*16+fr][kt*32+fq*8 ..+7]
  // = gA0 + mi*16*K + kt*32  (16B aligned; kt*64B fits the 13-bit imm)
  const unsigned short* gA0 = A + (size_t)(mbase + wm + fr)*K + fq*8;
  const unsigned short* gA1 = gA0 + (size_t)16*K;

  // ---- B LDS read bases: byte addr for (ni,kt) decomposes as
  //   fr*2K + ((fq^(fr&7)) ^ 4*(kt&1))*16  +  ni*32K + (kt>>1)*128
  // first part = two per-lane bases (kt parity), rest = imm offsets.
  const unsigned short* sBrE = sB + (size_t)fr*K + ( fq      ^ (fr & 7))*8;
  const unsigned short* sBrO = sB + (size_t)fr*K + ((fq | 4) ^ (fr & 7))*8;

  f32x4 acc[2][4];
  #pragma unroll
  for (int mi = 0; mi < 2; ++mi)
    #pragma unroll
    for (int ni = 0; ni < 4; ++ni) acc[mi][ni] = (f32x4){0.f, 0.f, 0.f, 0.f};

  __syncthreads();   // B panel resident (barrier drains vmcnt)

  #pragma unroll
  for (int kt = 0; kt < KSTEPS; ++kt) {
    s16x8 af0 = *(const s16x8*)(gA0 + kt*32);
    s16x8 af1 = *(const s16x8*)(gA1 + kt*32);
    const unsigned short* bb = (kt & 1) ? sBrO : sBrE;
    s16x8 bfr[4];
    #pragma unroll
    for (int ni = 0; ni < 4; ++ni)
      bfr[ni] = *(const s16x8*)(bb + ni*16*K + (kt >> 1)*64);
    #pragma unroll
    for (int ni = 0; ni < 4; ++ni) {
      acc[0][ni] = __builtin_amdgcn_mfma_f32_16x16x32_bf16(af0, bfr[ni], acc[0][ni], 0, 0, 0);
      acc[1][ni] = __builtin_amdgcn_mfma_f32_16x16x32_bf16(af1, bfr[ni], acc[1][ni], 0, 0, 0);
    }
  }

  // ---- epilogue: C layout per 16x16 tile: col=fr, row=fq*4+r (m89) ----
  if constexpr (EPI == 3) {
    #pragma unroll
    for (int ni = 0; ni < 4; ++ni) {
      int gn = nbase + ni*16 + fr;
      float bv = bias[gn];
      #pragma unroll
      for (int mi = 0; mi < 2; ++mi) {
        int gm0 = mbase + wm + mi*16 + fq*4;
        #pragma unroll
        for (int r = 0; r < 4; ++r) {
          size_t gm = (size_t)(gm0 + r);
          o_f[gm*DM + gn] = acc[mi][ni][r] + bv + resid[gm*DM + gn];
        }
      }
    }
  } else {
    __syncthreads();   // all waves done with sB -> reuse for C staging
    const bool do_silu = (EPI == 1) && (blockIdx.y < 12);   // panels 0-5 xp, 6-11 z
    // stage with pad-72 row stride (144B == 4 mod 32 banks -> ~2-way on writes)
    #pragma unroll
    for (int ni = 0; ni < 4; ++ni) {
      int cn = ni*16 + fr;
      float bv = bias[nbase + cn];
      #pragma unroll
      for (int mi = 0; mi < 2; ++mi) {
        int rm0 = wm + mi*16 + fq*4;
        #pragma unroll
        for (int r = 0; r < 4; ++r) {
          float c = acc[mi][ni][r] + bv;
          if constexpr (EPI == 1) { if (do_silu) c = silu_f(c); }
          else                    { c = (c > 20.f) ? c : __logf(1.f + __expf(c)); }
          smem[(rm0 + r)*72 + cn] = f2bf(c);
        }
      }
    }
    __syncthreads();
    unsigned short* dst;
    int colbase;
    if constexpr (EPI == 1) {
      int p = blockIdx.y;                       // 0..17
      dst = (p < 6) ? o_xp : (p < 12) ? o_z : o_dtin;
      colbase = (p % 6) * 64;
    } else {
      dst = o_bf; colbase = nbase;
    }
    const int rr = t >> 3, cc = (t & 7) * 8;
    #pragma unroll
    for (int it = 0; it < 4; ++it) {
      int row = rr + it*32;
      s16x8 v = *(const s16x8*)(smem + row*72 + cc);
      *(s16x8*)(dst + (size_t)(mbase + row)*DI + colbase + cc) = v;
    }
  }
}

// ---------------- chunked selective scan ----------------
__global__ __launch_bounds__(384) void scan_kernel(
    const unsigned short* __restrict__ xp, const unsigned short* __restrict__ dt,
    const unsigned short* __restrict__ zb, const float* __restrict__ A_log,
    const float* __restrict__ D_vec, unsigned short* __restrict__ yz) {
  int g  = blockIdx.x;
  int di = threadIdx.x;
  size_t base = (size_t)g * 32 * DI + di;
  float a[DS];
  #pragma unroll
  for (int s = 0; s < DS; ++s) a[s] = -__expf(A_log[di*DS + s]);
  float Dv = D_vec[di];
  float h[DS] = {0.f,0.f,0.f,0.f,0.f,0.f,0.f,0.f};
  for (int tt = 0; tt < 32; ++tt) {
    size_t idx = base + (size_t)tt * DI;
    float xv  = bf2f(xp[idx]);
    float dtv = bf2f(dt[idx]);
    float y = 0.f;
    #pragma unroll
    for (int s = 0; s < DS; ++s) {
      h[s] = h[s] * __expf(dtv * a[s]) + xv;
      y += h[s];
    }
    float zv = bf2f(zb[idx]);
    yz[idx] = f2bf(y * zv + xv * Dv);
  }
}

extern "C" void kernel_launch(void* const* d_in, const int* in_sizes, int n_in,
                              void* d_out, int out_size, void* d_ws, size_t ws_size,
                              hipStream_t stream) {
  const float* x     = (const float*)d_in[0];
  const float* gamma = (const float*)d_in[1];
  const float* beta  = (const float*)d_in[2];
  const float* W_in  = (const float*)d_in[3];
  const float* b_in  = (const float*)d_in[4];
  const float* W_dt  = (const float*)d_in[5];
  const float* b_dt  = (const float*)d_in[6];
  const float* A_log = (const float*)d_in[7];
  const float* D_vec = (const float*)d_in[8];
  const float* W_out = (const float*)d_in[9];
  const float* b_out = (const float*)d_in[10];
  float* out = (float*)d_out;

  char* ws = (char*)d_ws;
  size_t off = 0;
  auto alloc = [&](size_t bytes) -> char* {
    char* p = ws + off; off += (bytes + 255) & ~(size_t)255; return p;
  };
  unsigned short* xn    = (unsigned short*)alloc((size_t)M_*DM*2);
  unsigned short* xpb   = (unsigned short*)alloc((size_t)M_*DI*2);
  unsigned short* zb    = (unsigned short*)alloc((size_t)M_*DI*2);
  unsigned short* dtin  = (unsigned short*)alloc((size_t)M_*DI*2);
  unsigned short* dtb   = (unsigned short*)alloc((size_t)M_*DI*2);
  unsigned short* yzb   = dtin;   // dtin dead after GEMM2 -> reuse for yz
  unsigned short* winb  = (unsigned short*)alloc((size_t)3*DI*DM*2);
  unsigned short* wdtb  = (unsigned short*)alloc((size_t)DI*DI*2);
  unsigned short* woutb = (unsigned short*)alloc((size_t)DM*DI*2);

  cvt_kernel<<<dim3((3*DI*DM + 255)/256), 256, 0, stream>>>(W_in, W_dt, W_out, winb, wdtb, woutb);
  ln_kernel<<<dim3(M_/4), 256, 0, stream>>>(x, gamma, beta, xn);
  // GEMM1: xn[M,256] @ W_in[1152,256]^T -> silu(xp), silu(z), dtin
  gemm_ws<1, 8><<<dim3(M_/128, (3*DI)/64), 256, 0, stream>>>(
      xn, winb, b_in, xpb, zb, dtin, nullptr, nullptr, nullptr);
  // GEMM2: dtin[M,384] @ W_dt[384,384]^T ; softplus -> dt
  gemm_ws<2, 12><<<dim3(M_/128, DI/64), 256, 0, stream>>>(
      dtin, wdtb, b_dt, nullptr, nullptr, nullptr, dtb, nullptr, nullptr);
  // scan -> yz = y*z + xp*D
  scan_kernel<<<dim3(M_/32), DI, 0, stream>>>(xpb, dtb, zb, A_log, D_vec, yzb);
  // GEMM3: yz[M,384] @ W_out[256,384]^T + b_out + residual -> out (fp32)
  gemm_ws<3, 12><<<dim3(M_/128, DM/64), 256, 0, stream>>>(
      yzb, woutb, b_out, nullptr, nullptr, nullptr, nullptr, x, out);
}